// Round 9
// baseline (77.803 us; speedup 1.0000x reference)
//
#include <hip/hip_runtime.h>
#include <stdint.h>

// Problem dims
#define NB   4096   // batch rows (M)
#define KD   2048   // IN + S   (K)
#define ND   4096   // 4*S      (N, reordered: n -> gate=(n>>4)&3, s=(n>>6)*16+(n&15))
#define SD   1024   // state size

// GEMM tile (256x256, 8 waves = 2M x 4N, reads-at-top stagger pipeline)
#define BM   256
#define BN   256
#define BK   64
#define NKT  (KD / BK)   // 32 K-tiles

using f32x4  = __attribute__((ext_vector_type(4))) float;
using bf16x8 = __attribute__((ext_vector_type(8))) short;

typedef const __attribute__((address_space(1))) uint32_t* gas_u32;
typedef __attribute__((address_space(3))) uint32_t* las_u32;

__device__ __forceinline__ unsigned short f2bf(float f) {
    union { float f; uint32_t u; } c; c.f = f;
    uint32_t u = c.u;
    uint32_t r = (u + 0x7fffu + ((u >> 16) & 1u)) >> 16;  // RNE
    return (unsigned short)r;
}

__device__ __forceinline__ void async_load16(const void* gsrc, void* ldst) {
    __builtin_amdgcn_global_load_lds((gas_u32)gsrc, (las_u32)ldst, 16, 0, 0);
}

__device__ __forceinline__ float frcp(float x) { return __builtin_amdgcn_rcpf(x); }
__device__ __forceinline__ float sigm(float x) { return frcp(1.f + __expf(-x)); }
__device__ __forceinline__ float tanh_fast(float x) {
    return 1.f - 2.f * frcp(1.f + __expf(2.f * x));   // inf-safe
}

// ---------------------------------------------------------------------------
// Pack: fp32 -> bf16, X=[input|old_h]; W rows reordered so GEMM column
// n maps to weights row  gate*SD + (n>>6)*16 + (n&15),  gate=(n>>4)&3.
// ---------------------------------------------------------------------------
__global__ void pack_kernel(const float* __restrict__ input,
                            const float* __restrict__ old_h,
                            const float* __restrict__ weights,
                            const float* __restrict__ bias,
                            unsigned short* __restrict__ Xb,
                            unsigned short* __restrict__ Wb,
                            float* __restrict__ biasR) {
    const int XCH = NB * (KD / 4);
    const int WCH = ND * (KD / 4);
    const int BCH = ND / 4;
    const int total = XCH + WCH + BCH;
    for (int c = blockIdx.x * blockDim.x + threadIdx.x; c < total;
         c += gridDim.x * blockDim.x) {
        if (c < XCH) {
            int b  = c >> 9;
            int k  = (c & 511) << 2;
            const float* src = (k < 1024) ? (input + (size_t)b * 1024 + k)
                                          : (old_h + (size_t)b * 1024 + (k - 1024));
            float4 v = *reinterpret_cast<const float4*>(src);
            ushort4 o;
            o.x = f2bf(v.x); o.y = f2bf(v.y); o.z = f2bf(v.z); o.w = f2bf(v.w);
            *reinterpret_cast<ushort4*>(Xb + (size_t)b * KD + k) = o;
        } else if (c < XCH + WCH) {
            int cc = c - XCH;
            int n  = cc >> 9;
            int k  = (cc & 511) << 2;
            int srow = ((n >> 4) & 3) * SD + ((n >> 6) * 16 + (n & 15));
            float4 v = *reinterpret_cast<const float4*>(weights + (size_t)srow * KD + k);
            ushort4 o;
            o.x = f2bf(v.x); o.y = f2bf(v.y); o.z = f2bf(v.z); o.w = f2bf(v.w);
            *reinterpret_cast<ushort4*>(Wb + (size_t)n * KD + k) = o;
        } else {
            int n4 = (c - XCH - WCH) << 2;
            #pragma unroll
            for (int t = 0; t < 4; ++t) {
                int n = n4 + t;
                biasR[n] = bias[((n >> 4) & 3) * SD + ((n >> 6) * 16 + (n & 15))];
            }
        }
    }
}

// ---------------------------------------------------------------------------
// 256x256 GEMM + fused LSTM epilogue; 4 phases/K-tile, ONE tail barrier/phase.
// R9 structure ("stagger-overlap", m201 mechanism): each phase's ds_reads sit
// at the TOP of the phase and feed THAT phase's 16 MFMAs. NO manual lgkmcnt —
// the compiler emits split lgkmcnt(N) RAW waits, so each wave starts MFMAs as
// soon as ITS fragments land; other waves' drains overlap this wave's MFMA
// window (the overlap R4-R8's lgkm0-before-barrier lockstep destroyed).
// Phases (mq,kk): p0: a<-A(t).mq0k0, bk0<-B(t).k0 [8 rd]; p1: a<-mq0k1,
// bk1<-B(t).k1 [8]; p2: a<-mq1k0 [4]; p3: a<-mq1k1 [4]. MFMA16(mq,kk).
// Stage slots (1 half/phase): p0: A(t+1).A0, p1: A(t+1).A1 (other buf; its
// region A(t-1) last read p3(t-1)-top, drained by each wave's p3 MFMAs before
// p3(t-1) tail-bar -> all waves); p2: B(t+2).B0, p3: B(t+2).B1 (B(t) last
// read p1(t)-top, drained before p1 tail-bar). Cross-wave guarantee: every
// p-top read feeds a p-MFMA, so it drains before that wave's tail barrier.
// vmcnt(4) before p3 tail-bar: outstanding = [B(t+1)x4 (left by prev gate),
// A(t+1)x4, B(t+2)x4] = 12 -> drain 8 = A(t+1)+B(t+1) landed before their
// p0(t+1)-top reads; leaves B(t+2) 4 in flight (induction invariant).
// Prologue stages t0{B0,B1,A0,A1}+t1{B0,B1}=12 loads, vmcnt(4) -> t0 landed,
// t1.B in flight = same invariant at loop entry. kt wrap-around stages are
// ledger-legal garbage writes (same slot pattern as steady state).
// ---------------------------------------------------------------------------
#define SEG(DB, AB, HALF) (((((DB) * 2 + (AB)) * 2) + (HALF)) * 8192)

#define SBAR   __builtin_amdgcn_s_barrier()
#define SFENCE __builtin_amdgcn_sched_barrier(0)
#define ASM_VMCNT4 asm volatile("s_waitcnt vmcnt(4)" ::: "memory")

__launch_bounds__(512, 2)
__global__ void lstm_gemm(const unsigned short* __restrict__ Xb,
                          const unsigned short* __restrict__ Wb,
                          const float* __restrict__ biasR,
                          const float* __restrict__ old_cell,
                          float* __restrict__ new_h,
                          float* __restrict__ new_cell) {
    __shared__ unsigned short lds[65536];   // 128 KiB

    const int tid  = threadIdx.x;
    const int lane = tid & 63;
    const int wid  = tid >> 6;       // 0..7
    const int wm   = wid >> 2;       // 0..1  (M half owner)
    const int wn   = wid & 3;        // 0..3  (N quarter owner)
    const int l15  = lane & 15;
    const int krow = lane >> 4;      // 0..3

    // XCD-aware bijective swizzle (256 blocks, 8 XCDs)
    const int wg    = blockIdx.x;
    const int swz   = (wg & 7) * 32 + (wg >> 3);
    const int mblk  = swz >> 4;
    const int nblk  = swz & 15;
    const int rbase = mblk * BM;
    const int nbase = nblk * BN;

    // staging per-thread constants: half-tile = 128 rows x 64 cols = 1024 chunks
    const int c0 = tid, c1 = tid + 512;
    const int srow0 = c0 >> 3, sk0 = ((c0 & 7) ^ (srow0 & 7)) * 8;
    const int srow1 = c1 >> 3, sk1 = ((c1 & 7) ^ (srow1 & 7)) * 8;

    f32x4  acc[8][4] = {};
    bf16x8 a[4];       // A frags for current (mq,kk); overwritten each phase
    bf16x8 bk0[4];     // B frags, kk=0, all 4 j (live whole K-tile)
    bf16x8 bk1[4];     // B frags, kk=1

#define STAGE(PTR, TB, KT, DB, AB, HALF) do {                                   \
        async_load16((PTR) + (size_t)((TB) + (HALF) * 128 + srow0) * KD +       \
                         (KT) * BK + sk0,                                       \
                     lds + SEG(DB, AB, HALF) + c0 * 8);                         \
        async_load16((PTR) + (size_t)((TB) + (HALF) * 128 + srow1) * KD +       \
                         (KT) * BK + sk1,                                       \
                     lds + SEG(DB, AB, HALF) + c1 * 8);                         \
    } while (0)

    // 4 ds_read_b128: A fragments for quadrant MQ, k-half KK
#define LOAD_A4(DB, MQ, KK) do {                                                \
        const unsigned short* base_ = lds + SEG(DB, 0, 0) + wm * 8192;          \
        _Pragma("unroll") for (int i_ = 0; i_ < 4; ++i_) {                      \
            int r_ = (MQ) * 64 + i_ * 16 + l15;                                 \
            int s_ = (KK) * 4 + krow;                                           \
            a[i_] = *reinterpret_cast<const bf16x8*>(                           \
                base_ + r_ * 64 + ((s_ ^ (r_ & 7)) * 8));                       \
        }                                                                       \
    } while (0)

    // 4 ds_read_b128: B fragments, all 4 j of wave's 64-col panel, k-half KK
#define LOAD_B4(DST, DB, KK) do {                                               \
        const unsigned short* base_ = lds + SEG(DB, 1, 0) + (wn >> 1) * 8192;   \
        _Pragma("unroll") for (int j_ = 0; j_ < 4; ++j_) {                      \
            int r_ = (wn & 1) * 64 + j_ * 16 + l15;                             \
            int s_ = (KK) * 4 + krow;                                           \
            DST[j_] = *reinterpret_cast<const bf16x8*>(                         \
                base_ + r_ * 64 + ((s_ ^ (r_ & 7)) * 8));                       \
        }                                                                       \
    } while (0)

    // 16 MFMA: quadrant MQ x all 4 j, one k-half (a[], BB[] just read)
#define MMA16(MQ, BB) do {                                                      \
        _Pragma("unroll") for (int i_ = 0; i_ < 4; ++i_)                        \
        _Pragma("unroll") for (int j_ = 0; j_ < 4; ++j_)                        \
            acc[(MQ) * 4 + i_][j_] =                                            \
                __builtin_amdgcn_mfma_f32_16x16x32_bf16(                        \
                    a[i_], BB[j_], acc[(MQ) * 4 + i_][j_], 0, 0, 0);            \
    } while (0)

    // ---- prologue: t0 {B0,B1,A0,A1} -> buf0, t1 {B0,B1} -> buf1 ----
    STAGE(Wb, nbase, 0, 0, 1, 0);
    STAGE(Wb, nbase, 0, 0, 1, 1);
    STAGE(Xb, rbase, 0, 0, 0, 0);
    STAGE(Xb, rbase, 0, 0, 0, 1);
    STAGE(Wb, nbase, 1, 1, 1, 0);
    STAGE(Wb, nbase, 1, 1, 1, 1);
    ASM_VMCNT4;   // t0's 8 loads landed; t1.B (4) in flight
    SBAR;
    SFENCE;

    // ---- main loop: 4 phases per K-tile, reads-at-top, 1 barrier/phase ----
#define KBODY(TT, BUF) do {                                                     \
        const int kt1_ = ((TT) + 1) & (NKT - 1);                                \
        const int kt2_ = ((TT) + 2) & (NKT - 1);                                \
        /* p0: reads a(mq0,k0)+bk0; stage A(t+1).A0; MFMA(0,k0) */              \
        STAGE(Xb, rbase, kt1_, (BUF) ^ 1, 0, 0);                                \
        LOAD_A4(BUF, 0, 0);                                                     \
        LOAD_B4(bk0, BUF, 0);                                                   \
        MMA16(0, bk0);                                                          \
        SBAR; SFENCE;                                                           \
        /* p1: reads a(mq0,k1)+bk1; stage A(t+1).A1; MFMA(0,k1) */              \
        STAGE(Xb, rbase, kt1_, (BUF) ^ 1, 0, 1);                                \
        LOAD_A4(BUF, 0, 1);                                                     \
        LOAD_B4(bk1, BUF, 1);                                                   \
        MMA16(0, bk1);                                                          \
        SBAR; SFENCE;                                                           \
        /* p2: reads a(mq1,k0); stage B(t+2).B0; MFMA(1,k0) reuses bk0 */       \
        STAGE(Wb, nbase, kt2_, BUF, 1, 0);                                      \
        LOAD_A4(BUF, 1, 0);                                                     \
        MMA16(1, bk0);                                                          \
        SBAR; SFENCE;                                                           \
        /* p3: reads a(mq1,k1); stage B(t+2).B1; MFMA(1,k1); vmcnt gate */      \
        STAGE(Wb, nbase, kt2_, BUF, 1, 1);                                      \
        LOAD_A4(BUF, 1, 1);                                                     \
        MMA16(1, bk1);                                                          \
        ASM_VMCNT4;                                                             \
        SBAR; SFENCE;                                                           \
    } while (0)

    for (int t = 0; t < NKT; t += 2) {
        KBODY(t, 0);
        KBODY(t + 1, 1);
    }

    // ---- fused LSTM epilogue (reg-resident, zero-shuffle) ----
    const int s = (nblk * 4 + wn) * 16 + l15;
    float bg[4];
    #pragma unroll
    for (int jj = 0; jj < 4; ++jj)
        bg[jj] = biasR[nbase + wn * 64 + jj * 16 + l15];

    #pragma unroll
    for (int mi = 0; mi < 8; ++mi) {
        #pragma unroll
        for (int r = 0; r < 4; ++r) {
            const int row = rbase + wm * 128 + mi * 16 + krow * 4 + r;
            float fg = sigm(acc[mi][0][r] + bg[0]);
            float ig = sigm(acc[mi][1][r] + bg[1]);
            float og = sigm(acc[mi][2][r] + bg[2]);
            float gg = tanh_fast(acc[mi][3][r] + bg[3]);
            float oc = old_cell[(size_t)row * SD + s];
            float nc = fmaf(fg, oc, ig * gg);
            float nh = og * tanh_fast(nc);
            new_h[(size_t)row * SD + s]    = nh;
            new_cell[(size_t)row * SD + s] = nc;
        }
    }
}

extern "C" void kernel_launch(void* const* d_in, const int* in_sizes, int n_in,
                              void* d_out, int out_size, void* d_ws, size_t ws_size,
                              hipStream_t stream) {
    const float* input    = (const float*)d_in[0];
    const float* old_h    = (const float*)d_in[1];
    const float* old_cell = (const float*)d_in[2];
    const float* weights  = (const float*)d_in[3];
    const float* bias     = (const float*)d_in[4];

    unsigned short* Xb  = (unsigned short*)d_ws;                             // 16 MiB
    unsigned short* Wb  = (unsigned short*)((char*)d_ws + (size_t)16777216); // 16 MiB
    float*          bR  = (float*)((char*)d_ws + (size_t)33554432);          // 16 KiB

    float* out_h = (float*)d_out;
    float* out_c = out_h + (size_t)NB * SD;

    pack_kernel<<<2048, 256, 0, stream>>>(input, old_h, weights, bias, Xb, Wb, bR);
    lstm_gemm<<<(NB / BM) * (ND / BN), 512, 0, stream>>>(Xb, Wb, bR, old_cell,
                                                         out_h, out_c);
}